// Round 13
// baseline (329.134 us; speedup 1.0000x reference)
//
#include <hip/hip_runtime.h>
#include <hip/hip_bf16.h>

using bf16 = __hip_bfloat16;
using uint = unsigned int;
typedef __bf16 bf16x8 __attribute__((ext_vector_type(8)));
typedef float f32x4 __attribute__((ext_vector_type(4)));

#define MFMA16(a, b, c) __builtin_amdgcn_mfma_f32_16x16x32_bf16((a), (b), (c), 0, 0, 0)

// N=65536, P=6, D=256, out=(N,27) fp32.
// ZERO-BARRIER point-partitioned design: each wave owns 32 points end-to-end.
//   Phase B: all 256 d1 for own pts (A = W1t streamed), H1 -> per-wave LDS
//            section, stored directly in B-fragment layout (address-transform),
//            XOR-swizzled (b64 writes 4/bank, b128 reads 8/bank = optimal).
//   Phase C: H1 B-frags held in 64 regs; stream full W2t (A) from L2;
//            H2 kept as 64 packed bf16x2 regs (never hits memory).
//   Phase D: B-frags built from H2 regs via intra-wave ds_bpermute.
// No __syncthreads anywhere (same-wave LDS ordering via lgkmcnt).
// Regs ~214 < 256 (2 waves/SIMD, 8 waves/CU); LDS 74KB -> 2 blocks/CU.
// Cost: W2t read by every wave (4x L2 traffic ~45us floor, sequential/prefetchable)
// in exchange for eliminating all barrier drains + spill.
// Bias: b1 inside layer-1 GEMM (X slot 17 = 1.0, W1t k=17 = b1); b2/b3 preloaded
// into MFMA accumulators.
// Feature order k': 0-7 frame, 8-10 tpts, 11-13 bigpts, 14-16 viewdir,
//                   17 = 1.0, 18-31 zero.
//
// ws (bf16): W1t [P][256 d1][32 k'] @0 (49152)
//            W2t [P][256 d2][256 d1] @49152 (393216)
//            W3t [P][32 r][256 d2] @442368 (49152)  r<20:W3, r==20:Wocc, else 0

__global__ void prep_kernel(const float* __restrict__ W1, const float* __restrict__ b1,
                            const float* __restrict__ W2, const float* __restrict__ W3,
                            const float* __restrict__ Wocc, __bf16* __restrict__ ws) {
  const int t = blockIdx.x * 256 + threadIdx.x;
  if (t < 49152) {  // W2t: one 8-wide k-chunk per thread, lanes n-major => coalesced
    const int p = t >> 13, r = t & 8191, n = r >> 5, c = r & 31;
    const float* src = W2 + p * 65536 + c * 8 * 256 + n;
    bf16x8 v;
#pragma unroll
    for (int j = 0; j < 8; ++j) v[j] = (__bf16)src[j * 256];
    *reinterpret_cast<bf16x8*>(&ws[49152 + p * 65536 + n * 256 + c * 8]) = v;
  } else if (t < 55296) {  // W1t (reordered features, b1 at k=17)
    const int u = t - 49152;
    const int p = u >> 10, r = u & 1023, n = r >> 2, c = r & 3;
    bf16x8 v;
#pragma unroll
    for (int j = 0; j < 8; ++j) {
      const int k = c * 8 + j;
      float x = 0.f;
      if (k < 17) {
        const int ko = (k < 8) ? k + 3 : ((k < 11) ? k - 8 : k);
        x = W1[p * 4352 + ko * 256 + n];
      } else if (k == 17) {
        x = b1[p * 256 + n];
      }
      v[j] = (__bf16)x;
    }
    *reinterpret_cast<bf16x8*>(&ws[p * 8192 + n * 32 + c * 8]) = v;
  } else if (t < 61440) {  // W3t (W3 || Wocc || zeros)
    const int u = t - 55296;
    const int p = u >> 10, r = u & 1023, row = r >> 5, c = r & 31;
    bf16x8 v;
#pragma unroll
    for (int j = 0; j < 8; ++j) {
      const int k = c * 8 + j;
      float x = 0.f;
      if (row < 20)       x = W3[p * 5120 + k * 20 + row];
      else if (row == 20) x = Wocc[p * 256 + k];
      v[j] = (__bf16)x;
    }
    *reinterpret_cast<bf16x8*>(&ws[442368 + p * 8192 + row * 256 + c * 8]) = v;
  }
}

__device__ __forceinline__ uint packrelu(float a, float b) {
  __bf16 x = (__bf16)fmaxf(a, 0.f);
  __bf16 y = (__bf16)fmaxf(b, 0.f);
  return (uint)__builtin_bit_cast(unsigned short, x) |
         ((uint)__builtin_bit_cast(unsigned short, y) << 16);
}
__device__ __forceinline__ uint pack2(float a, float b) {
  __bf16 x = (__bf16)a;
  __bf16 y = (__bf16)b;
  return (uint)__builtin_bit_cast(unsigned short, x) |
         ((uint)__builtin_bit_cast(unsigned short, y) << 16);
}

__global__ __launch_bounds__(256, 2) void tpose_main(
    const float* __restrict__ tpts, const float* __restrict__ bigpts,
    const float* __restrict__ viewdir, const float* __restrict__ frame,
    const float* __restrict__ b2g, const float* __restrict__ b3g,
    const float* __restrict__ boccg, const int* __restrict__ tflag,
    const __bf16* __restrict__ ws, float* __restrict__ out) {
  const __bf16* __restrict__ W1t = ws;
  const __bf16* __restrict__ W2t = ws + 49152;
  const __bf16* __restrict__ W3t = ws + 442368;

  __shared__ __align__(16) __bf16 Xs[128 * 40];  // per-wave 32 rows x 40   10 KB
  __shared__ __align__(16) uint  H1s[16384];     // per-wave 4096 dw        64 KB

  const int tid = threadIdx.x;
  const int w = tid >> 6;
  const int lane = tid & 63;
  const int lq = lane >> 4;
  const int ln = lane & 15;
  const int swz = (ln & 7) << 3;        // dword-col XOR key (bits 3-5)
  const int n0 = blockIdx.x * 128;
  const int wpt0 = n0 + w * 32;         // wave's first point

  // ---- one-time X row init (per-wave; 2 lanes per point) ----
  const int prow = lane >> 1;           // local pt 0..31
  const int role = lane & 1;
  uint* xr = (uint*)&Xs[(w * 32 + prow) * 40];  // row as 20 dwords
  if (role == 0) {
    bf16x8 f8;
#pragma unroll
    for (int j = 0; j < 8; ++j) f8[j] = (__bf16)frame[j];
    *reinterpret_cast<bf16x8*>(xr) = f8;        // dw 0-3: slots 0-7
  } else {
#pragma unroll
    for (int i = 9; i < 16; ++i) xr[i] = 0;     // dw 9-15: slots 18-31 = 0
  }

  // ---- prefetch features + flags for part 0 ----
  float pre[6];
  {
    const int b3i = (wpt0 + prow) * 18;  // ((pt)*6 + 0)*3
    if (role == 0) {
#pragma unroll
      for (int i = 0; i < 3; ++i) { pre[i] = tpts[b3i + i]; pre[3 + i] = bigpts[b3i + i]; }
    } else {
#pragma unroll
      for (int i = 0; i < 3; ++i) pre[i] = viewdir[b3i + i];
    }
  }
  float flv[2];
#pragma unroll
  for (int nt = 0; nt < 2; ++nt)
    flv[nt] = (tflag[(wpt0 + nt * 16 + ln) * 6] != 0) ? 1.f : 0.f;

  float psum0[2][4] = {{0.f, 0.f, 0.f, 0.f}, {0.f, 0.f, 0.f, 0.f}};
  float psum1[2][4] = {{0.f, 0.f, 0.f, 0.f}, {0.f, 0.f, 0.f, 0.f}};

  uint* const h1w = &H1s[w * 4096];
  const int idxA = ((2 * (lq & 1)) * 16 + ln) * 4;  // bpermute byte index, j<2
  const int idxB = idxA + 64;                        // j>=2 (src lane +16)

  for (int p = 0; p < 6; ++p) {
    // ---- Phase A: store prefetched features (pure LDS, own wave's rows) ----
    if (role == 0) {
      xr[4] = pack2(pre[0], pre[1]);   // slots 8,9   (tpts0,1)
      xr[5] = pack2(pre[2], pre[3]);   // slots 10,11 (tpts2, big0)
      xr[6] = pack2(pre[4], pre[5]);   // slots 12,13 (big1,2)
    } else {
      xr[7] = pack2(pre[0], pre[1]);   // slots 14,15 (view0,1)
      xr[8] = pack2(pre[2], 1.0f);     // slots 16,17 (view2, bias-1)
    }

    // prefetch part p+1 (consumed next iteration)
    const int pn = (p < 5) ? p + 1 : 5;
    float fln[2];
    {
      const int b3i = ((wpt0 + prow) * 6 + pn) * 3;
      if (role == 0) {
#pragma unroll
        for (int i = 0; i < 3; ++i) { pre[i] = tpts[b3i + i]; pre[3 + i] = bigpts[b3i + i]; }
      } else {
#pragma unroll
        for (int i = 0; i < 3; ++i) pre[i] = viewdir[b3i + i];
      }
#pragma unroll
      for (int nt = 0; nt < 2; ++nt)
        fln[nt] = (tflag[(wpt0 + nt * 16 + ln) * 6 + pn] != 0) ? 1.f : 0.f;
    }

    // ---- Phase B: H1 = relu(W1^T X), all 256 d1 for own 32 pts ----
    const bf16x8 xb0 = *reinterpret_cast<const bf16x8*>(&Xs[(w * 32 + ln) * 40 + lq * 8]);
    const bf16x8 xb1 = *reinterpret_cast<const bf16x8*>(&Xs[(w * 32 + 16 + ln) * 40 + lq * 8]);
    const __bf16* __restrict__ w1p = W1t + p * 8192 + ln * 32 + lq * 8;
#pragma unroll
    for (int mt = 0; mt < 16; ++mt) {
      const bf16x8 aw = *reinterpret_cast<const bf16x8*>(w1p + mt * 512);
      f32x4 z = {0.f, 0.f, 0.f, 0.f};
      const f32x4 h0 = MFMA16(aw, xb0, z);
      const f32x4 h1 = MFMA16(aw, xb1, z);
      const int cc = (mt * 8 + lq * 2) ^ swz;
      uint2 s0, s1;
      s0.x = packrelu(h0[0], h0[1]); s0.y = packrelu(h0[2], h0[3]);
      s1.x = packrelu(h1[0], h1[1]); s1.y = packrelu(h1[2], h1[3]);
      *reinterpret_cast<uint2*>(&h1w[ln * 128 + cc]) = s0;
      *reinterpret_cast<uint2*>(&h1w[(16 + ln) * 128 + cc]) = s1;
    }

    // ---- Phase C: H2 = relu(W2^T H1 + b2); H1 frags in regs, W2 streamed ----
    bf16x8 hf[8][2];
#pragma unroll
    for (int kk = 0; kk < 8; ++kk)
#pragma unroll
      for (int nt = 0; nt < 2; ++nt)
        hf[kk][nt] = *reinterpret_cast<const bf16x8*>(
            &h1w[(nt * 16 + ln) * 128 + ((kk * 16 + lq * 4) ^ swz)]);

    uint h2p[16][2][2];  // [mt2][nt][u] packed bf16x2 (64 regs)
    const __bf16* __restrict__ w2p = W2t + p * 65536 + ln * 256 + lq * 8;
#pragma unroll
    for (int m2 = 0; m2 < 16; m2 += 2) {
      const f32x4 bv0 = *reinterpret_cast<const f32x4*>(&b2g[p * 256 + m2 * 16 + lq * 4]);
      const f32x4 bv1 = *reinterpret_cast<const f32x4*>(&b2g[p * 256 + m2 * 16 + 16 + lq * 4]);
      f32x4 aA0 = bv0, aA1 = bv0, aB0 = bv1, aB1 = bv1;
#pragma unroll
      for (int kk = 0; kk < 8; ++kk) {
        const bf16x8 a2A = *reinterpret_cast<const bf16x8*>(w2p + m2 * 4096 + kk * 32);
        const bf16x8 a2B = *reinterpret_cast<const bf16x8*>(w2p + (m2 + 1) * 4096 + kk * 32);
        aA0 = MFMA16(a2A, hf[kk][0], aA0);
        aA1 = MFMA16(a2A, hf[kk][1], aA1);
        aB0 = MFMA16(a2B, hf[kk][0], aB0);
        aB1 = MFMA16(a2B, hf[kk][1], aB1);
      }
      h2p[m2][0][0] = packrelu(aA0[0], aA0[1]); h2p[m2][0][1] = packrelu(aA0[2], aA0[3]);
      h2p[m2][1][0] = packrelu(aA1[0], aA1[1]); h2p[m2][1][1] = packrelu(aA1[2], aA1[3]);
      h2p[m2 + 1][0][0] = packrelu(aB0[0], aB0[1]); h2p[m2 + 1][0][1] = packrelu(aB0[2], aB0[3]);
      h2p[m2 + 1][1][0] = packrelu(aB1[0], aB1[1]); h2p[m2 + 1][1][1] = packrelu(aB1[2], aB1[3]);
    }

    // ---- Phase D: raw||occ = W3^T H2 + b3; B-frags via ds_bpermute ----
    f32x4 acc3[2][2];
    {
      float b3v[2][4];
#pragma unroll
      for (int mt = 0; mt < 2; ++mt)
#pragma unroll
        for (int r = 0; r < 4; ++r) {
          const int d = mt * 16 + lq * 4 + r;
          float v = 0.f;
          if (d < 20)       v = b3g[p * 20 + d];
          else if (d == 20) v = boccg[p];
          b3v[mt][r] = v;
        }
#pragma unroll
      for (int mt = 0; mt < 2; ++mt)
#pragma unroll
        for (int nt = 0; nt < 2; ++nt)
#pragma unroll
          for (int r = 0; r < 4; ++r) acc3[mt][nt][r] = b3v[mt][r];
    }
    const __bf16* __restrict__ w3p = W3t + p * 8192 + ln * 256 + lq * 8;
#pragma unroll
    for (int kk = 0; kk < 8; ++kk) {
      const bf16x8 a30 = *reinterpret_cast<const bf16x8*>(w3p + kk * 32);
      const bf16x8 a31 = *reinterpret_cast<const bf16x8*>(w3p + 4096 + kk * 32);
#pragma unroll
      for (int nt = 0; nt < 2; ++nt) {
        uint bw[4];
#pragma unroll
        for (int j = 0; j < 4; ++j) {
          const int idx = (j < 2) ? idxA : idxB;
          const int u = j & 1;
          const uint lo = (uint)__builtin_amdgcn_ds_bpermute(idx, (int)h2p[2 * kk][nt][u]);
          const uint hi = (uint)__builtin_amdgcn_ds_bpermute(idx, (int)h2p[2 * kk + 1][nt][u]);
          bw[j] = (lq < 2) ? lo : hi;
        }
        union { uint u4[4]; bf16x8 v; } cv;
        cv.u4[0] = bw[0]; cv.u4[1] = bw[1]; cv.u4[2] = bw[2]; cv.u4[3] = bw[3];
        acc3[0][nt] = MFMA16(a30, cv.v, acc3[0][nt]);
        acc3[1][nt] = MFMA16(a31, cv.v, acc3[1][nt]);
      }
    }

    // ---- Epilogue ----
#pragma unroll
    for (int nt = 0; nt < 2; ++nt) {
      const int pt = wpt0 + nt * 16 + ln;
#pragma unroll
      for (int r = 0; r < 4; ++r) psum0[nt][r] += flv[nt] * acc3[0][nt][r];
      if (lq == 0) {
#pragma unroll
        for (int r = 0; r < 4; ++r) psum1[nt][r] += flv[nt] * acc3[1][nt][r];
      } else if (lq == 1) {  // dim 20 = occ (r=0)
        const float occ = 1.f / (1.f + __expf(-acc3[1][nt][0]));
        out[pt * 27 + 21 + p] = flv[nt] * occ;
        psum1[nt][0] += flv[nt] * occ;
      }
    }

    flv[0] = fln[0];
    flv[1] = fln[1];
  }  // p loop

  const float inv6 = 1.f / 6.f;
#pragma unroll
  for (int nt = 0; nt < 2; ++nt) {
    const int pt = wpt0 + nt * 16 + ln;
#pragma unroll
    for (int r = 0; r < 4; ++r) out[pt * 27 + lq * 4 + r] = psum0[nt][r] * inv6;
    if (lq == 0) {
#pragma unroll
      for (int r = 0; r < 4; ++r) out[pt * 27 + 16 + r] = psum1[nt][r] * inv6;
    } else if (lq == 1) {
      out[pt * 27 + 20] = psum1[nt][0] * inv6;
    }
  }
}

extern "C" void kernel_launch(void* const* d_in, const int* in_sizes, int n_in,
                              void* d_out, int out_size, void* d_ws, size_t ws_size,
                              hipStream_t stream) {
  const float* tpts    = (const float*)d_in[0];
  const float* bigpts  = (const float*)d_in[1];
  const float* viewdir = (const float*)d_in[2];
  const float* frame   = (const float*)d_in[5];
  const float* W1      = (const float*)d_in[6];
  const float* b1      = (const float*)d_in[7];
  const float* W2      = (const float*)d_in[8];
  const float* b2      = (const float*)d_in[9];
  const float* W3      = (const float*)d_in[10];
  const float* b3      = (const float*)d_in[11];
  const float* Wocc    = (const float*)d_in[12];
  const float* bocc    = (const float*)d_in[13];
  const int*   tflag   = (const int*)d_in[14];
  __bf16* ws  = (__bf16*)d_ws;
  float*  out = (float*)d_out;

  prep_kernel<<<240, 256, 0, stream>>>(W1, b1, W2, W3, Wocc, ws);
  tpose_main<<<512, 256, 0, stream>>>(tpts, bigpts, viewdir, frame, b2, b3,
                                      bocc, tflag, ws, out);
}

// Round 14
// 277.643 us; speedup vs baseline: 1.1855x; 1.1855x over previous
//
#include <hip/hip_runtime.h>
#include <hip/hip_bf16.h>

using bf16 = __hip_bfloat16;
using uint = unsigned int;
typedef __bf16 bf16x8 __attribute__((ext_vector_type(8)));
typedef __bf16 bf16x4v __attribute__((ext_vector_type(4)));
typedef float f32x4 __attribute__((ext_vector_type(4)));

#define MFMA16(a, b, c) __builtin_amdgcn_mfma_f32_16x16x32_bf16((a), (b), (c), 0, 0, 0)

// N=65536, P=6, D=256, out=(N,27) fp32. Transposed MFMA (r12 lineage = best):
// A = weights (m = out-feature), B = points (n = point). 128 pts/block,
// 256 threads (4 waves): wave w owns features [64w,64w+64) in B/C, pts
// [32w,32w+32) in D. 4 barriers/part.
// REGISTER MODEL (r5-r13): unified VGPR+AGPR file, waves/SIMD steps at
// 64/128/256 total. Operating point 2/SIMD (8 waves/CU). r12 sat at 256-exact
// (acc[4][8]=128 + arch 128) -> ~60MB structural spill. Fix: phases B/C run
// two nt-groups with acc[4][4] (64) reused; phase-C group-0 results PARKED in
// 32 packed-bf16 regs (relu pre-applied = store format), written after
// barrier (3). Peak ~204/256 -> slack ~50 -> no spill, no extra barrier,
// ILP kept (16 indep chains/group). r13's zero-barrier design disproved:
// barriers are not the tax, ILP+spill are.
// Bias: b1 inside layer-1 GEMM (X slot 17 = 1.0, W1t k=17 = b1); b2/b3
// preloaded into MFMA accumulators (C-operand additive).
// Feature order k': 0-7 frame, 8-10 tpts, 11-13 bigpts, 14-16 viewdir,
//                   17 = 1.0, 18-31 zero.
//
// ws (bf16): W1t [P][256 d1][32 k'] @0 (49152)
//            W2t [P][256 d2][256 d1] @49152 (393216)
//            W3t [P][32 r][256 d2] @442368 (49152)  r<20:W3, r==20:Wocc, else 0

__global__ void prep_kernel(const float* __restrict__ W1, const float* __restrict__ b1,
                            const float* __restrict__ W2, const float* __restrict__ W3,
                            const float* __restrict__ Wocc, __bf16* __restrict__ ws) {
  const int t = blockIdx.x * 256 + threadIdx.x;
  if (t < 49152) {  // W2t: one 8-wide k-chunk per thread
    const int p = t >> 13, r = t & 8191, n = r >> 5, c = r & 31;
    const float* src = W2 + p * 65536 + c * 8 * 256 + n;
    bf16x8 v;
#pragma unroll
    for (int j = 0; j < 8; ++j) v[j] = (__bf16)src[j * 256];
    *reinterpret_cast<bf16x8*>(&ws[49152 + p * 65536 + n * 256 + c * 8]) = v;
  } else if (t < 55296) {  // W1t (reordered features, b1 at k=17)
    const int u = t - 49152;
    const int p = u >> 10, r = u & 1023, n = r >> 2, c = r & 3;
    bf16x8 v;
#pragma unroll
    for (int j = 0; j < 8; ++j) {
      const int k = c * 8 + j;
      float x = 0.f;
      if (k < 17) {
        const int ko = (k < 8) ? k + 3 : ((k < 11) ? k - 8 : k);
        x = W1[p * 4352 + ko * 256 + n];
      } else if (k == 17) {
        x = b1[p * 256 + n];
      }
      v[j] = (__bf16)x;
    }
    *reinterpret_cast<bf16x8*>(&ws[p * 8192 + n * 32 + c * 8]) = v;
  } else if (t < 61440) {  // W3t (W3 || Wocc || zeros)
    const int u = t - 55296;
    const int p = u >> 10, r = u & 1023, row = r >> 5, c = r & 31;
    bf16x8 v;
#pragma unroll
    for (int j = 0; j < 8; ++j) {
      const int k = c * 8 + j;
      float x = 0.f;
      if (row < 20)       x = W3[p * 5120 + k * 20 + row];
      else if (row == 20) x = Wocc[p * 256 + k];
      v[j] = (__bf16)x;
    }
    *reinterpret_cast<bf16x8*>(&ws[442368 + p * 8192 + row * 256 + c * 8]) = v;
  }
}

__device__ __forceinline__ uint packrelu(float a, float b) {
  __bf16 x = (__bf16)fmaxf(a, 0.f);
  __bf16 y = (__bf16)fmaxf(b, 0.f);
  return (uint)__builtin_bit_cast(unsigned short, x) |
         ((uint)__builtin_bit_cast(unsigned short, y) << 16);
}

// Hf [pt][256 d] (32 16B-chunks/row), XOR swizzle chunk^=(pt&7): b64 writes
// 4 accesses/bank, b128 reads 8/bank (both at throughput minimum).
__global__ __launch_bounds__(256, 2) void tpose_main(
    const float* __restrict__ tpts, const float* __restrict__ bigpts,
    const float* __restrict__ viewdir, const float* __restrict__ frame,
    const float* __restrict__ b2g, const float* __restrict__ b3g,
    const float* __restrict__ boccg, const int* __restrict__ tflag,
    const __bf16* __restrict__ ws, float* __restrict__ out) {
  const __bf16* __restrict__ W1t = ws;
  const __bf16* __restrict__ W2t = ws + 49152;
  const __bf16* __restrict__ W3t = ws + 442368;

  __shared__ __align__(16) __bf16 Xf[128 * 40];    // [pt][k' pad 40]  10 KB
  __shared__ __align__(16) __bf16 Hf[128 * 256];   // swizzled         64 KB

  const int tid = threadIdx.x;
  const int w = tid >> 6;
  const int lane = tid & 63;
  const int lq = lane >> 4;
  const int ln = lane & 15;
  const int e = ln & 7;           // swizzle key (row & 7 == ln & 7 at every use)
  const int n0 = blockIdx.x * 128;

  // one-time X init: frame octet, 1.0 at slot 17, zeros 18-31
  if (tid < 128) {
    bf16x8 f8;
#pragma unroll
    for (int j = 0; j < 8; ++j) f8[j] = (__bf16)frame[j];
    *reinterpret_cast<bf16x8*>(&Xf[tid * 40]) = f8;
    bf16x8 z = {};
    z[1] = (__bf16)1.0f;  // slot 17 = constant-1 (bias feature)
    *reinterpret_cast<bf16x8*>(&Xf[tid * 40 + 16]) = z;
    bf16x8 z2 = {};
    *reinterpret_cast<bf16x8*>(&Xf[tid * 40 + 24]) = z2;
  }

  const int role = tid & 3;  // 0: tpts, 1: bigpts, 2: viewdir, 3: idle
  const float* __restrict__ dynsrc =
      (role == 0) ? tpts : (role == 1) ? bigpts : viewdir;

  // prefetch state for part 0
  float pre[2][3];
  float flv[2];
#pragma unroll
  for (int pass = 0; pass < 2; ++pass) {
    const int pt = (tid >> 2) + pass * 64;
    const int base3 = (n0 + pt) * 18;  // p=0
#pragma unroll
    for (int i = 0; i < 3; ++i) pre[pass][i] = dynsrc[base3 + i];
  }
#pragma unroll
  for (int s = 0; s < 2; ++s)
    flv[s] = (tflag[(n0 + w * 32 + s * 16 + ln) * 6] != 0) ? 1.f : 0.f;

  float psum0[2][4] = {{0.f, 0.f, 0.f, 0.f}, {0.f, 0.f, 0.f, 0.f}};
  float psum1[2][4] = {{0.f, 0.f, 0.f, 0.f}, {0.f, 0.f, 0.f, 0.f}};

  for (int p = 0; p < 6; ++p) {
    // ---- Phase A: store prefetched features (pure LDS) ----
    if (role < 3) {
#pragma unroll
      for (int pass = 0; pass < 2; ++pass) {
        const int pt = (tid >> 2) + pass * 64;
#pragma unroll
        for (int i = 0; i < 3; ++i)
          Xf[pt * 40 + 8 + role * 3 + i] = (__bf16)pre[pass][i];
      }
    }

    // prefetch part p+1 (latency hidden behind phases B-D)
    const int pn = (p < 5) ? p + 1 : 5;
    float fln[2];
#pragma unroll
    for (int pass = 0; pass < 2; ++pass) {
      const int pt = (tid >> 2) + pass * 64;
      const int base3 = ((n0 + pt) * 6 + pn) * 3;
#pragma unroll
      for (int i = 0; i < 3; ++i) pre[pass][i] = dynsrc[base3 + i];
    }
#pragma unroll
    for (int s = 0; s < 2; ++s)
      fln[s] = (tflag[(n0 + w * 32 + s * 16 + ln) * 6 + pn] != 0) ? 1.f : 0.f;

    // hoist phase-B weight loads above the barrier (global, LDS-independent)
    bf16x8 aw[4];
#pragma unroll
    for (int mt = 0; mt < 4; ++mt)
      aw[mt] = *reinterpret_cast<const bf16x8*>(
          &W1t[p * 8192 + (w * 64 + mt * 16 + ln) * 32 + lq * 8]);

    __syncthreads();  // (1) X visible; prev part's phase-D Hf reads done

    // ---- Phase B: H1 = relu(W1^T X); two nt-groups, acc[4][4] reused ----
#pragma unroll
    for (int g = 0; g < 2; ++g) {
      f32x4 acc[4][4];
#pragma unroll
      for (int mt = 0; mt < 4; ++mt)
#pragma unroll
        for (int nt = 0; nt < 4; ++nt) acc[mt][nt] = f32x4{0.f, 0.f, 0.f, 0.f};
#pragma unroll
      for (int nt = 0; nt < 4; ++nt) {
        const bf16x8 xb = *reinterpret_cast<const bf16x8*>(
            &Xf[((g * 4 + nt) * 16 + ln) * 40 + lq * 8]);
#pragma unroll
        for (int mt = 0; mt < 4; ++mt) acc[mt][nt] = MFMA16(aw[mt], xb, acc[mt][nt]);
      }
#pragma unroll
      for (int mt = 0; mt < 4; ++mt) {
        const int c = w * 8 + mt * 2 + (lq >> 1);
        const int off = ((c ^ e) << 3) + (lq & 1) * 4;
#pragma unroll
        for (int nt = 0; nt < 4; ++nt) {
          bf16x4v hv;
#pragma unroll
          for (int r = 0; r < 4; ++r) hv[r] = (__bf16)fmaxf(acc[mt][nt][r], 0.f);
          *reinterpret_cast<bf16x4v*>(&Hf[((g * 4 + nt) * 16 + ln) * 256 + off]) = hv;
        }
      }
    }

    __syncthreads();  // (2) H1 visible

    // ---- Phase C: H2 = relu(W2^T H1 + b2); group 0 parked, group 1 in acc ----
    const __bf16* __restrict__ w2p = W2t + p * 65536 + (w * 64 + ln) * 256 + lq * 8;
    uint park[4][4][2];  // group-0 results, packed bf16 (32 regs)
    f32x4 acc[4][4];
#pragma unroll
    for (int g = 0; g < 2; ++g) {
      {
        f32x4 b2v[4];
#pragma unroll
        for (int mt = 0; mt < 4; ++mt)
          b2v[mt] = *reinterpret_cast<const f32x4*>(
              &b2g[p * 256 + w * 64 + mt * 16 + lq * 4]);
#pragma unroll
        for (int mt = 0; mt < 4; ++mt)
#pragma unroll
          for (int nt = 0; nt < 4; ++nt) acc[mt][nt] = b2v[mt];  // bias preload
      }
      bf16x8 a2[4];
#pragma unroll
      for (int mt = 0; mt < 4; ++mt)
        a2[mt] = *reinterpret_cast<const bf16x8*>(w2p + mt * 4096);
#pragma unroll
      for (int kk = 0; kk < 8; ++kk) {
        bf16x8 a2n[4];
        if (kk < 7) {
#pragma unroll
          for (int mt = 0; mt < 4; ++mt)
            a2n[mt] = *reinterpret_cast<const bf16x8*>(
                w2p + mt * 4096 + (kk + 1) * 32);
        }
#pragma unroll
        for (int nt = 0; nt < 4; ++nt) {
          const bf16x8 hb = *reinterpret_cast<const bf16x8*>(
              &Hf[((g * 4 + nt) * 16 + ln) * 256 + (((kk * 4 + lq) ^ e) << 3)]);
#pragma unroll
          for (int mt = 0; mt < 4; ++mt) acc[mt][nt] = MFMA16(a2[mt], hb, acc[mt][nt]);
        }
#pragma unroll
        for (int mt = 0; mt < 4; ++mt) a2[mt] = a2n[mt];
      }
      if (g == 0) {  // park group-0 (relu + pack = final store format)
#pragma unroll
        for (int mt = 0; mt < 4; ++mt)
#pragma unroll
          for (int nt = 0; nt < 4; ++nt) {
            park[mt][nt][0] = packrelu(acc[mt][nt][0], acc[mt][nt][1]);
            park[mt][nt][1] = packrelu(acc[mt][nt][2], acc[mt][nt][3]);
          }
      }
    }

    __syncthreads();  // (3) H1 reads done before overwrite

#pragma unroll
    for (int mt = 0; mt < 4; ++mt) {
      const int c = w * 8 + mt * 2 + (lq >> 1);
      const int off = ((c ^ e) << 3) + (lq & 1) * 4;
#pragma unroll
      for (int nt = 0; nt < 4; ++nt) {  // group 0 from park
        uint2 s;
        s.x = park[mt][nt][0]; s.y = park[mt][nt][1];
        *reinterpret_cast<uint2*>(&Hf[(nt * 16 + ln) * 256 + off]) = s;
      }
#pragma unroll
      for (int nt = 0; nt < 4; ++nt) {  // group 1 from acc
        bf16x4v hv;
#pragma unroll
        for (int r = 0; r < 4; ++r) hv[r] = (__bf16)fmaxf(acc[mt][nt][r], 0.f);
        *reinterpret_cast<bf16x4v*>(&Hf[((4 + nt) * 16 + ln) * 256 + off]) = hv;
      }
    }

    __syncthreads();  // (4) H2 visible

    // ---- Phase D: raw||occ = W3^T H2 + b3; wave w -> pts [32w, 32w+32) ----
    f32x4 acc3[2][2];
    {
      float b3v[2][4];
#pragma unroll
      for (int mt = 0; mt < 2; ++mt)
#pragma unroll
        for (int r = 0; r < 4; ++r) {
          const int d = mt * 16 + lq * 4 + r;
          float v = 0.f;
          if (d < 20)       v = b3g[p * 20 + d];
          else if (d == 20) v = boccg[p];
          b3v[mt][r] = v;
        }
#pragma unroll
      for (int mt = 0; mt < 2; ++mt)
#pragma unroll
        for (int s = 0; s < 2; ++s)
#pragma unroll
          for (int r = 0; r < 4; ++r) acc3[mt][s][r] = b3v[mt][r];  // bias preload
    }
    const __bf16* __restrict__ w3p = W3t + p * 8192 + ln * 256 + lq * 8;
#pragma unroll
    for (int kk = 0; kk < 8; ++kk) {
      bf16x8 a3[2];
#pragma unroll
      for (int mt = 0; mt < 2; ++mt)
        a3[mt] = *reinterpret_cast<const bf16x8*>(w3p + mt * 4096 + kk * 32);
#pragma unroll
      for (int s = 0; s < 2; ++s) {
        const bf16x8 hb = *reinterpret_cast<const bf16x8*>(
            &Hf[(w * 32 + s * 16 + ln) * 256 + (((kk * 4 + lq) ^ e) << 3)]);
#pragma unroll
        for (int mt = 0; mt < 2; ++mt) acc3[mt][s] = MFMA16(a3[mt], hb, acc3[mt][s]);
      }
    }

    // Epilogue (bias already in acc3)
#pragma unroll
    for (int s = 0; s < 2; ++s) {
      const int pt = n0 + w * 32 + s * 16 + ln;
#pragma unroll
      for (int r = 0; r < 4; ++r) psum0[s][r] += flv[s] * acc3[0][s][r];
      if (lq == 0) {
#pragma unroll
        for (int r = 0; r < 4; ++r) psum1[s][r] += flv[s] * acc3[1][s][r];
      } else if (lq == 1) {  // dim 20 = occ (r=0)
        const float occ = 1.f / (1.f + __expf(-acc3[1][s][0]));
        out[pt * 27 + 21 + p] = flv[s] * occ;
        psum1[s][0] += flv[s] * occ;
      }
    }

    flv[0] = fln[0];
    flv[1] = fln[1];
  }  // p loop

  const float inv6 = 1.f / 6.f;
#pragma unroll
  for (int s = 0; s < 2; ++s) {
    const int pt = n0 + w * 32 + s * 16 + ln;
#pragma unroll
    for (int r = 0; r < 4; ++r) out[pt * 27 + lq * 4 + r] = psum0[s][r] * inv6;
    if (lq == 0) {
#pragma unroll
      for (int r = 0; r < 4; ++r) out[pt * 27 + 16 + r] = psum1[s][r] * inv6;
    } else if (lq == 1) {
      out[pt * 27 + 20] = psum1[s][0] * inv6;
    }
  }
}

extern "C" void kernel_launch(void* const* d_in, const int* in_sizes, int n_in,
                              void* d_out, int out_size, void* d_ws, size_t ws_size,
                              hipStream_t stream) {
  const float* tpts    = (const float*)d_in[0];
  const float* bigpts  = (const float*)d_in[1];
  const float* viewdir = (const float*)d_in[2];
  const float* frame   = (const float*)d_in[5];
  const float* W1      = (const float*)d_in[6];
  const float* b1      = (const float*)d_in[7];
  const float* W2      = (const float*)d_in[8];
  const float* b2      = (const float*)d_in[9];
  const float* W3      = (const float*)d_in[10];
  const float* b3      = (const float*)d_in[11];
  const float* Wocc    = (const float*)d_in[12];
  const float* bocc    = (const float*)d_in[13];
  const int*   tflag   = (const int*)d_in[14];
  __bf16* ws  = (__bf16*)d_ws;
  float*  out = (float*)d_out;

  prep_kernel<<<240, 256, 0, stream>>>(W1, b1, W2, W3, Wocc, ws);
  tpose_main<<<512, 256, 0, stream>>>(tpts, bigpts, viewdir, frame, b2, b3,
                                      bocc, tflag, ws, out);
}

// Round 15
// 199.585 us; speedup vs baseline: 1.6491x; 1.3911x over previous
//
#include <hip/hip_runtime.h>
#include <hip/hip_bf16.h>

using bf16 = __hip_bfloat16;
using uint = unsigned int;
typedef __bf16 bf16x8 __attribute__((ext_vector_type(8)));
typedef __bf16 bf16x4v __attribute__((ext_vector_type(4)));
typedef float f32x4 __attribute__((ext_vector_type(4)));

#define MFMA16(a, b, c) __builtin_amdgcn_mfma_f32_16x16x32_bf16((a), (b), (c), 0, 0, 0)

// N=65536, P=6, D=256, out=(N,27) fp32. Transposed MFMA (r12 base = best 117us):
// A = weights (m = out-feature), B = points (n = point). 128 pts/block,
// 256 threads (4 waves): wave w owns features [64w,64w+64) in B/C, pts
// [32w,32w+32) in D. 4 barriers/part.
// TRAFFIC MODEL (r12 counters re-derived): WRITE 44MB = out RMW from per-part
// tocc scatter-stores (stride-27 partial lines dirtied 6x); FETCH 42MB =
// inputs 16MB + RMW line fills. NOT register spill (arch fits 128; acc 128
// AGPR; 256 exact). Fix this round: occ -> LDS Ts per part; after p-loop,
// stage all 27 dims into freed Hf as packed [pt][27] fp32 (= global layout)
// and do one coalesced float4 copy-out. Every out line written once, fully.
// Bias: b1 inside layer-1 GEMM (X slot 17 = 1.0, W1t k=17 = b1); b2/b3
// preloaded into MFMA accumulators (C-operand additive).
// Feature order k': 0-7 frame, 8-10 tpts, 11-13 bigpts, 14-16 viewdir,
//                   17 = 1.0, 18-31 zero.
//
// ws (bf16): W1t [P][256 d1][32 k'] @0 (49152)
//            W2t [P][256 d2][256 d1] @49152 (393216)
//            W3t [P][32 r][256 d2] @442368 (49152)  r<20:W3, r==20:Wocc, else 0

__global__ void prep_kernel(const float* __restrict__ W1, const float* __restrict__ b1,
                            const float* __restrict__ W2, const float* __restrict__ W3,
                            const float* __restrict__ Wocc, __bf16* __restrict__ ws) {
  const int t = blockIdx.x * 256 + threadIdx.x;
  if (t < 49152) {  // W2t: one 8-wide k-chunk per thread
    const int p = t >> 13, r = t & 8191, n = r >> 5, c = r & 31;
    const float* src = W2 + p * 65536 + c * 8 * 256 + n;
    bf16x8 v;
#pragma unroll
    for (int j = 0; j < 8; ++j) v[j] = (__bf16)src[j * 256];
    *reinterpret_cast<bf16x8*>(&ws[49152 + p * 65536 + n * 256 + c * 8]) = v;
  } else if (t < 55296) {  // W1t (reordered features, b1 at k=17)
    const int u = t - 49152;
    const int p = u >> 10, r = u & 1023, n = r >> 2, c = r & 3;
    bf16x8 v;
#pragma unroll
    for (int j = 0; j < 8; ++j) {
      const int k = c * 8 + j;
      float x = 0.f;
      if (k < 17) {
        const int ko = (k < 8) ? k + 3 : ((k < 11) ? k - 8 : k);
        x = W1[p * 4352 + ko * 256 + n];
      } else if (k == 17) {
        x = b1[p * 256 + n];
      }
      v[j] = (__bf16)x;
    }
    *reinterpret_cast<bf16x8*>(&ws[p * 8192 + n * 32 + c * 8]) = v;
  } else if (t < 61440) {  // W3t (W3 || Wocc || zeros)
    const int u = t - 55296;
    const int p = u >> 10, r = u & 1023, row = r >> 5, c = r & 31;
    bf16x8 v;
#pragma unroll
    for (int j = 0; j < 8; ++j) {
      const int k = c * 8 + j;
      float x = 0.f;
      if (row < 20)       x = W3[p * 5120 + k * 20 + row];
      else if (row == 20) x = Wocc[p * 256 + k];
      v[j] = (__bf16)x;
    }
    *reinterpret_cast<bf16x8*>(&ws[442368 + p * 8192 + row * 256 + c * 8]) = v;
  }
}

// Hf [pt][256 d] (32 16B-chunks/row), XOR swizzle chunk^=(pt&7): b64 writes
// 4 accesses/bank, b128 reads 8/bank (both at throughput minimum).
__global__ __launch_bounds__(256, 2) void tpose_main(
    const float* __restrict__ tpts, const float* __restrict__ bigpts,
    const float* __restrict__ viewdir, const float* __restrict__ frame,
    const float* __restrict__ b2g, const float* __restrict__ b3g,
    const float* __restrict__ boccg, const int* __restrict__ tflag,
    const __bf16* __restrict__ ws, float* __restrict__ out) {
  const __bf16* __restrict__ W1t = ws;
  const __bf16* __restrict__ W2t = ws + 49152;
  const __bf16* __restrict__ W3t = ws + 442368;

  __shared__ __align__(16) __bf16 Xf[128 * 40];    // [pt][k' pad 40]  10 KB
  __shared__ __align__(16) __bf16 Hf[128 * 256];   // swizzled H / out stage 64 KB
  __shared__ float Ts[128 * 6];                    // per-part occ      3 KB

  const int tid = threadIdx.x;
  const int w = tid >> 6;
  const int lane = tid & 63;
  const int lq = lane >> 4;
  const int ln = lane & 15;
  const int e = ln & 7;           // swizzle key (row & 7 == ln & 7 at every use)
  const int n0 = blockIdx.x * 128;

  // one-time X init: frame octet, 1.0 at slot 17, zeros 18-31
  if (tid < 128) {
    bf16x8 f8;
#pragma unroll
    for (int j = 0; j < 8; ++j) f8[j] = (__bf16)frame[j];
    *reinterpret_cast<bf16x8*>(&Xf[tid * 40]) = f8;
    bf16x8 z = {};
    z[1] = (__bf16)1.0f;  // slot 17 = constant-1 (bias feature)
    *reinterpret_cast<bf16x8*>(&Xf[tid * 40 + 16]) = z;
    bf16x8 z2 = {};
    *reinterpret_cast<bf16x8*>(&Xf[tid * 40 + 24]) = z2;
  }

  const int role = tid & 3;  // 0: tpts, 1: bigpts, 2: viewdir, 3: idle
  const float* __restrict__ dynsrc =
      (role == 0) ? tpts : (role == 1) ? bigpts : viewdir;

  // prefetch state for part 0
  float pre[2][3];
  float flv[2];
#pragma unroll
  for (int pass = 0; pass < 2; ++pass) {
    const int pt = (tid >> 2) + pass * 64;
    const int base3 = (n0 + pt) * 18;  // p=0
#pragma unroll
    for (int i = 0; i < 3; ++i) pre[pass][i] = dynsrc[base3 + i];
  }
#pragma unroll
  for (int s = 0; s < 2; ++s)
    flv[s] = (tflag[(n0 + w * 32 + s * 16 + ln) * 6] != 0) ? 1.f : 0.f;

  float psum0[2][4] = {{0.f, 0.f, 0.f, 0.f}, {0.f, 0.f, 0.f, 0.f}};
  float psum1[2][4] = {{0.f, 0.f, 0.f, 0.f}, {0.f, 0.f, 0.f, 0.f}};

  for (int p = 0; p < 6; ++p) {
    // ---- Phase A: store prefetched features (pure LDS) ----
    if (role < 3) {
#pragma unroll
      for (int pass = 0; pass < 2; ++pass) {
        const int pt = (tid >> 2) + pass * 64;
#pragma unroll
        for (int i = 0; i < 3; ++i)
          Xf[pt * 40 + 8 + role * 3 + i] = (__bf16)pre[pass][i];
      }
    }

    // prefetch part p+1 (latency hidden behind phases B-D)
    const int pn = (p < 5) ? p + 1 : 5;
    float fln[2];
#pragma unroll
    for (int pass = 0; pass < 2; ++pass) {
      const int pt = (tid >> 2) + pass * 64;
      const int base3 = ((n0 + pt) * 6 + pn) * 3;
#pragma unroll
      for (int i = 0; i < 3; ++i) pre[pass][i] = dynsrc[base3 + i];
    }
#pragma unroll
    for (int s = 0; s < 2; ++s)
      fln[s] = (tflag[(n0 + w * 32 + s * 16 + ln) * 6 + pn] != 0) ? 1.f : 0.f;

    // hoist phase-B weight loads above the barrier (global, LDS-independent)
    bf16x8 aw[4];
#pragma unroll
    for (int mt = 0; mt < 4; ++mt)
      aw[mt] = *reinterpret_cast<const bf16x8*>(
          &W1t[p * 8192 + (w * 64 + mt * 16 + ln) * 32 + lq * 8]);

    __syncthreads();  // (1) X visible; prev part's phase-D Hf reads done

    // ---- Phase B: H1 = relu(W1^T X) (bias inside GEMM via slot 17) ----
    f32x4 acc[4][8];
#pragma unroll
    for (int mt = 0; mt < 4; ++mt)
#pragma unroll
      for (int nt = 0; nt < 8; ++nt) acc[mt][nt] = f32x4{0.f, 0.f, 0.f, 0.f};
#pragma unroll
    for (int nt = 0; nt < 8; ++nt) {
      const bf16x8 xb =
          *reinterpret_cast<const bf16x8*>(&Xf[(nt * 16 + ln) * 40 + lq * 8]);
#pragma unroll
      for (int mt = 0; mt < 4; ++mt) acc[mt][nt] = MFMA16(aw[mt], xb, acc[mt][nt]);
    }
#pragma unroll
    for (int mt = 0; mt < 4; ++mt) {
      const int c = w * 8 + mt * 2 + (lq >> 1);
      const int off = ((c ^ e) << 3) + (lq & 1) * 4;
#pragma unroll
      for (int nt = 0; nt < 8; ++nt) {
        bf16x4v hv;
#pragma unroll
        for (int r = 0; r < 4; ++r) hv[r] = (__bf16)fmaxf(acc[mt][nt][r], 0.f);
        *reinterpret_cast<bf16x4v*>(&Hf[(nt * 16 + ln) * 256 + off]) = hv;
      }
    }

    __syncthreads();  // (2) H1 visible

    // ---- Phase C: H2 = relu(W2^T H1 + b2); b2 pre-init into acc ----
    {
      f32x4 b2v[4];
#pragma unroll
      for (int mt = 0; mt < 4; ++mt)
        b2v[mt] = *reinterpret_cast<const f32x4*>(
            &b2g[p * 256 + w * 64 + mt * 16 + lq * 4]);
#pragma unroll
      for (int mt = 0; mt < 4; ++mt)
#pragma unroll
        for (int nt = 0; nt < 8; ++nt) acc[mt][nt] = b2v[mt];  // bias preload
    }
    const __bf16* __restrict__ w2p = W2t + p * 65536 + (w * 64 + ln) * 256 + lq * 8;
    {
      bf16x8 a2[4];
#pragma unroll
      for (int mt = 0; mt < 4; ++mt)
        a2[mt] = *reinterpret_cast<const bf16x8*>(w2p + mt * 4096);
#pragma unroll
      for (int kk = 0; kk < 8; ++kk) {
        bf16x8 a2n[4];
        if (kk < 7) {
#pragma unroll
          for (int mt = 0; mt < 4; ++mt)
            a2n[mt] = *reinterpret_cast<const bf16x8*>(
                w2p + mt * 4096 + (kk + 1) * 32);
        }
#pragma unroll
        for (int nt = 0; nt < 8; ++nt) {
          const bf16x8 hb = *reinterpret_cast<const bf16x8*>(
              &Hf[(nt * 16 + ln) * 256 + (((kk * 4 + lq) ^ e) << 3)]);
#pragma unroll
          for (int mt = 0; mt < 4; ++mt) acc[mt][nt] = MFMA16(a2[mt], hb, acc[mt][nt]);
        }
#pragma unroll
        for (int mt = 0; mt < 4; ++mt) a2[mt] = a2n[mt];
      }
    }

    __syncthreads();  // (3) H1 reads done before overwrite

#pragma unroll
    for (int mt = 0; mt < 4; ++mt) {
      const int c = w * 8 + mt * 2 + (lq >> 1);
      const int off = ((c ^ e) << 3) + (lq & 1) * 4;
#pragma unroll
      for (int nt = 0; nt < 8; ++nt) {
        bf16x4v hv;
#pragma unroll
        for (int r = 0; r < 4; ++r) hv[r] = (__bf16)fmaxf(acc[mt][nt][r], 0.f);
        *reinterpret_cast<bf16x4v*>(&Hf[(nt * 16 + ln) * 256 + off]) = hv;
      }
    }

    __syncthreads();  // (4) H2 visible

    // ---- Phase D: raw||occ = W3^T H2 + b3; wave w -> pts [32w, 32w+32) ----
    f32x4 acc3[2][2];
    {
      float b3v[2][4];
#pragma unroll
      for (int mt = 0; mt < 2; ++mt)
#pragma unroll
        for (int r = 0; r < 4; ++r) {
          const int d = mt * 16 + lq * 4 + r;
          float v = 0.f;
          if (d < 20)       v = b3g[p * 20 + d];
          else if (d == 20) v = boccg[p];
          b3v[mt][r] = v;
        }
#pragma unroll
      for (int mt = 0; mt < 2; ++mt)
#pragma unroll
        for (int s = 0; s < 2; ++s)
#pragma unroll
          for (int r = 0; r < 4; ++r) acc3[mt][s][r] = b3v[mt][r];  // bias preload
    }
    const __bf16* __restrict__ w3p = W3t + p * 8192 + ln * 256 + lq * 8;
#pragma unroll
    for (int kk = 0; kk < 8; ++kk) {
      bf16x8 a3[2];
#pragma unroll
      for (int mt = 0; mt < 2; ++mt)
        a3[mt] = *reinterpret_cast<const bf16x8*>(w3p + mt * 4096 + kk * 32);
#pragma unroll
      for (int s = 0; s < 2; ++s) {
        const bf16x8 hb = *reinterpret_cast<const bf16x8*>(
            &Hf[(w * 32 + s * 16 + ln) * 256 + (((kk * 4 + lq) ^ e) << 3)]);
#pragma unroll
        for (int mt = 0; mt < 2; ++mt) acc3[mt][s] = MFMA16(a3[mt], hb, acc3[mt][s]);
      }
    }

    // Epilogue (bias already in acc3); occ -> LDS, no global stores here
#pragma unroll
    for (int s = 0; s < 2; ++s) {
      const int ptl = w * 32 + s * 16 + ln;
#pragma unroll
      for (int r = 0; r < 4; ++r) psum0[s][r] += flv[s] * acc3[0][s][r];
      if (lq == 0) {
#pragma unroll
        for (int r = 0; r < 4; ++r) psum1[s][r] += flv[s] * acc3[1][s][r];
      } else if (lq == 1) {  // dim 20 = occ (r=0)
        const float occ = 1.f / (1.f + __expf(-acc3[1][s][0]));
        Ts[ptl * 6 + p] = flv[s] * occ;
        psum1[s][0] += flv[s] * occ;
      }
    }

    flv[0] = fln[0];
    flv[1] = fln[1];
  }  // p loop

  __syncthreads();  // all phase-D Hf reads done; Hf now free for staging

  // ---- stage outputs into Hf as packed [pt][27] fp32 (= global layout) ----
  float* __restrict__ Sg = reinterpret_cast<float*>(Hf);
  const float inv6 = 1.f / 6.f;
#pragma unroll
  for (int s = 0; s < 2; ++s) {
    const int ptl = w * 32 + s * 16 + ln;
#pragma unroll
    for (int r = 0; r < 4; ++r) Sg[ptl * 27 + lq * 4 + r] = psum0[s][r] * inv6;
    if (lq == 0) {
#pragma unroll
      for (int r = 0; r < 4; ++r) Sg[ptl * 27 + 16 + r] = psum1[s][r] * inv6;
    } else if (lq == 1) {
      Sg[ptl * 27 + 20] = psum1[s][0] * inv6;
#pragma unroll
      for (int i = 0; i < 6; ++i) Sg[ptl * 27 + 21 + i] = Ts[ptl * 6 + i];
    }
  }

  __syncthreads();  // staging visible

  // ---- coalesced copy-out: 128*27 = 3456 dwords = 864 float4 ----
  {
    const f32x4* __restrict__ src4 = reinterpret_cast<const f32x4*>(Sg);
    f32x4* __restrict__ dst4 = reinterpret_cast<f32x4*>(out + n0 * 27);
    for (int i = tid; i < 864; i += 256) dst4[i] = src4[i];
  }
}

extern "C" void kernel_launch(void* const* d_in, const int* in_sizes, int n_in,
                              void* d_out, int out_size, void* d_ws, size_t ws_size,
                              hipStream_t stream) {
  const float* tpts    = (const float*)d_in[0];
  const float* bigpts  = (const float*)d_in[1];
  const float* viewdir = (const float*)d_in[2];
  const float* frame   = (const float*)d_in[5];
  const float* W1      = (const float*)d_in[6];
  const float* b1      = (const float*)d_in[7];
  const float* W2      = (const float*)d_in[8];
  const float* b2      = (const float*)d_in[9];
  const float* W3      = (const float*)d_in[10];
  const float* b3      = (const float*)d_in[11];
  const float* Wocc    = (const float*)d_in[12];
  const float* bocc    = (const float*)d_in[13];
  const int*   tflag   = (const int*)d_in[14];
  __bf16* ws  = (__bf16*)d_ws;
  float*  out = (float*)d_out;

  prep_kernel<<<240, 256, 0, stream>>>(W1, b1, W2, W3, Wocc, ws);
  tpose_main<<<512, 256, 0, stream>>>(tpts, bigpts, viewdir, frame, b2, b3,
                                      bocc, tflag, ws, out);
}